// Round 7
// baseline (334.983 us; speedup 1.0000x reference)
//
#include <hip/hip_runtime.h>
#include <hip/hip_fp16.h>
#include <hip/hip_bf16.h>

constexpr int BB  = 8;
constexpr int NN  = 4096;
constexpr int CC  = 256;
constexpr int CKK = 32;

typedef __attribute__((ext_vector_type(8))) short    short8;  // 8 x bf16 bits
typedef __attribute__((ext_vector_type(8))) _Float16 half8;
typedef __attribute__((ext_vector_type(4))) _Float16 half4;
typedef __attribute__((ext_vector_type(4))) float    f32x4;

#define GPTR(x) ((const __attribute__((address_space(1))) void*)(x))
#define LPTR(x) ((__attribute__((address_space(3))) void*)(x))

__device__ __forceinline__ unsigned short bf16_bits(float v) {
    __hip_bfloat16 h = __float2bfloat16(v);
    return *reinterpret_cast<unsigned short*>(&h);
}
__device__ __forceinline__ float bf16_val(unsigned short u) {
    __hip_bfloat16 h = *reinterpret_cast<__hip_bfloat16*>(&u);
    return __bfloat162float(h);
}

// ---------------------------------------------------------------------------
// K0a: weight transpose + bf16 hi/lo split into WT[576][256]:
// rows 0..255 = Wh cols, 256..287 = Wf, 288..319 = Wg, 320..575 = Wo.
// ---------------------------------------------------------------------------
__global__ __launch_bounds__(256) void prep_kernel(
    const float* __restrict__ Wf, const float* __restrict__ Wg,
    const float* __restrict__ Wh, const float* __restrict__ Wo,
    unsigned short* __restrict__ WThi, unsigned short* __restrict__ WTlo)
{
    const int n = blockIdx.x;
    const int k = threadIdx.x;
    float v;
    if      (n < 256) v = Wh[k * 256 + n];
    else if (n < 288) v = Wf[k * 32 + (n - 256)];
    else if (n < 320) v = Wg[k * 32 + (n - 288)];
    else              v = Wo[k * 256 + (n - 320)];
    const unsigned short hi = bf16_bits(v);
    WThi[n * 256 + k] = hi;
    WTlo[n * 256 + k] = bf16_bits(v - bf16_val(hi));
}

// ---------------------------------------------------------------------------
// K0b: x fp32 -> bf16 hi/lo (done ONCE; removes per-GEMM split VALU)
// ---------------------------------------------------------------------------
__global__ __launch_bounds__(256) void xsplit_kernel(
    const float* __restrict__ x,
    unsigned short* __restrict__ xhi, unsigned short* __restrict__ xlo)
{
    const size_t i = ((size_t)blockIdx.x * 256 + threadIdx.x) * 8;
    float a[8];
    *(float4*)&a[0] = *(const float4*)&x[i];
    *(float4*)&a[4] = *(const float4*)&x[i + 4];
    short8 hi, lo;
    #pragma unroll
    for (int j = 0; j < 8; ++j) {
        const unsigned short h = bf16_bits(a[j]);
        hi[j] = (short)h;
        lo[j] = (short)bf16_bits(a[j] - bf16_val(h));
    }
    *(short8*)&xhi[i] = hi;
    *(short8*)&xlo[i] = lo;
}

// ---------------------------------------------------------------------------
// K1: projections GEMM [32768 x 256] @ [256 x 320], A pre-split bf16.
// Block = 256 M x 64 N (grid 128 x 5); wave = 64M x 64N.
// hhT stored fp16 transposed [b][c][n], 8-key segments XOR-swizzled by (c&7)
// within each 64-key group (so attn's LDS reads are conflict-free after a
// verbatim global->LDS DMA).
// ---------------------------------------------------------------------------
__global__ __launch_bounds__(256) void fgh_kernel(
    const unsigned short* __restrict__ xhi, const unsigned short* __restrict__ xlo,
    const unsigned short* __restrict__ WThi, const unsigned short* __restrict__ WTlo,
    const float* __restrict__ bf, const float* __restrict__ bg,
    const float* __restrict__ bh,
    _Float16* __restrict__ fbuf, _Float16* __restrict__ gbuf,
    _Float16* __restrict__ hhT)
{
    const int tid = threadIdx.x, w = tid >> 6, lane = tid & 63;
    const int ln = lane & 15, lq = lane >> 4;
    const int px0 = blockIdx.x * 256 + w * 64;
    const int n0  = blockIdx.y * 64;

    f32x4 acc[4][4];   // [mt][nt]
    #pragma unroll
    for (int i = 0; i < 4; ++i)
        #pragma unroll
        for (int j = 0; j < 4; ++j) acc[i][j] = {0.f, 0.f, 0.f, 0.f};

    #pragma unroll 1
    for (int kc = 0; kc < 8; ++kc) {
        const int k0 = kc * 32;
        short8 Ahi[4], Alo[4];
        #pragma unroll
        for (int mt = 0; mt < 4; ++mt) {
            const size_t aoff = (size_t)(px0 + mt * 16 + ln) * CC + k0 + lq * 8;
            Ahi[mt] = *(const short8*)&xhi[aoff];
            Alo[mt] = *(const short8*)&xlo[aoff];
        }
        #pragma unroll
        for (int nt = 0; nt < 4; ++nt) {
            const size_t boff = (size_t)(n0 + nt * 16 + ln) * 256 + k0 + lq * 8;
            const short8 Bhi = *(const short8*)&WThi[boff];
            const short8 Blo = *(const short8*)&WTlo[boff];
            #pragma unroll
            for (int mt = 0; mt < 4; ++mt) {
                acc[mt][nt] = __builtin_amdgcn_mfma_f32_16x16x32_bf16(Ahi[mt], Bhi, acc[mt][nt], 0, 0, 0);
                acc[mt][nt] = __builtin_amdgcn_mfma_f32_16x16x32_bf16(Ahi[mt], Blo, acc[mt][nt], 0, 0, 0);
                acc[mt][nt] = __builtin_amdgcn_mfma_f32_16x16x32_bf16(Alo[mt], Bhi, acc[mt][nt], 0, 0, 0);
            }
        }
    }

    const int b = px0 >> 12;
    if (blockIdx.y < 4) {
        // hh channels -> transposed fp16 store, segment-swizzled
        #pragma unroll
        for (int nt = 0; nt < 4; ++nt) {
            const int c = n0 + nt * 16 + ln;
            const float bias = bh[c];
            #pragma unroll
            for (int mt = 0; mt < 4; ++mt) {
                half4 hv;
                #pragma unroll
                for (int r = 0; r < 4; ++r) hv[r] = (_Float16)(acc[mt][nt][r] + bias);
                const int npix = (px0 & (NN - 1)) + mt * 16 + lq * 4;
                const int nsw  = (npix & ~63) | (((((npix >> 3) & 7) ^ (ln & 7)) << 3) | (npix & 7));
                *(half4*)&hhT[((size_t)(b * CC + c)) * NN + nsw] = hv;
            }
        }
    } else {
        // f (nt 0,1), g (nt 2,3): d = (nt&1)*16 + ln
        #pragma unroll
        for (int nt = 0; nt < 4; ++nt) {
            const int d = (nt & 1) * 16 + ln;
            const float bias = (nt < 2) ? bf[d] : bg[d];
            _Float16* dst = (nt < 2) ? fbuf : gbuf;
            #pragma unroll
            for (int mt = 0; mt < 4; ++mt)
                #pragma unroll
                for (int r = 0; r < 4; ++r)
                    dst[(size_t)(px0 + mt * 16 + lq * 4 + r) * CKK + d] =
                        (_Float16)(acc[mt][nt][r] + bias);
        }
    }
}

// ---------------------------------------------------------------------------
// K2: MFMA flash attention — fully wave-independent compute.
// Block = 64 q; wave = 16 q x 256 c, covers ALL keys (no S dup, no shared P).
// S^T C-layout -> K32 PV A-frag via register shuffles: shuffle BOTH candidate
// tiles from the source lane, select post-shuffle by destination lq (the
// pre-shuffle select was R6's bug: __shfl returns the source lane's value,
// whose lq-based selection differs from the destination's).
// hh tiles staged via global_load_lds (dbuf, 64 KB).
// Epilogue emits o as bf16 hi/lo for the out GEMM.
// ---------------------------------------------------------------------------
__global__ __launch_bounds__(256, 2) void attn_kernel(
    const _Float16* __restrict__ fbuf, const _Float16* __restrict__ gbuf,
    const _Float16* __restrict__ hhT,
    unsigned short* __restrict__ ohi, unsigned short* __restrict__ olo)
{
    __shared__ _Float16 Ht[2][256 * 64];   // 64 KB: [buf][c][64 keys, swizzled]

    const int tid = threadIdx.x, w = tid >> 6, lane = tid & 63;
    const int ln = lane & 15, lq = lane >> 4;
    const int b  = blockIdx.x & 7;               // batch == XCD
    const int q0 = (blockIdx.x >> 3) * 64;
    const int qw = q0 + w * 16;                  // this wave's first query

    const f32x4 zero = {0.f, 0.f, 0.f, 0.f};
    constexpr float LOG2E = 1.4426950408889634f;
    const _Float16* fb = fbuf + (size_t)b * NN * CKK;

    // DMA source: lane covers (c = w*64 + i*8 + lane/8, 8 keys at (lane&7)*8)
    const _Float16* gsrc = hhT + ((size_t)(b * CC + w * 64 + (lane >> 3))) * NN + (lane & 7) * 8;

    // prologue: stage tile 0 into buf 0 (latency hidden by pass 1)
    #pragma unroll
    for (int i = 0; i < 8; ++i)
        __builtin_amdgcn_global_load_lds(GPTR(gsrc + (size_t)i * 8 * NN),
                                         LPTR(&Ht[0][(w * 64 + i * 8) * 64]), 16, 0, 0);

    // persistent g B-frag: B[k=d][n=q] for this wave's 16 queries
    const half8 Bg = *(const half8*)&gbuf[(size_t)(b * NN + qw + ln) * CKK + lq * 8];

    // ---- pass 1: rowmax over ALL keys (wave-local; no cross-wave merge) ----
    half8 Af[4], Afn[4];
    #pragma unroll
    for (int kt = 0; kt < 4; ++kt)
        Af[kt] = *(const half8*)&fb[(size_t)(kt * 16 + ln) * CKK + lq * 8];
    float mx = -1e30f;
    #pragma unroll 1
    for (int j0 = 0; j0 < NN; j0 += 64) {
        if (j0 + 64 < NN) {
            #pragma unroll
            for (int kt = 0; kt < 4; ++kt)
                Afn[kt] = *(const half8*)&fb[(size_t)(j0 + 64 + kt * 16 + ln) * CKK + lq * 8];
        }
        #pragma unroll
        for (int kt = 0; kt < 4; ++kt) {
            const f32x4 s = __builtin_amdgcn_mfma_f32_16x16x32_f16(Af[kt], Bg, zero, 0, 0, 0);
            mx = fmaxf(mx, fmaxf(fmaxf(s[0], s[1]), fmaxf(s[2], s[3])));
        }
        #pragma unroll
        for (int kt = 0; kt < 4; ++kt) Af[kt] = Afn[kt];
    }
    mx = fmaxf(mx, __shfl_xor(mx, 16));
    mx = fmaxf(mx, __shfl_xor(mx, 32));
    const float mk = mx * LOG2E;                 // per-lane, q = ln

    // ---- pass 2 ----
    f32x4 O[16];
    #pragma unroll
    for (int ct = 0; ct < 16; ++ct) O[ct] = zero;
    float psum = 0.f;

    #pragma unroll
    for (int kt = 0; kt < 4; ++kt)
        Af[kt] = *(const half8*)&fb[(size_t)(kt * 16 + ln) * CKK + lq * 8];

    const int s0lane = ln + (lq & 1) * 32;
    const int s1lane = s0lane + 16;
    const bool sel = (lq & 2) != 0;   // destination tile selector (kt = lq>>1)

    #pragma unroll 1
    for (int j0 = 0; j0 < NN; j0 += 64) {
        const int buf = (j0 >> 6) & 1;

        __asm__ volatile("s_waitcnt vmcnt(0)" ::: "memory");
        __syncthreads();   // DMA for this tile (issued last iter) now visible

        if (j0 + 64 < NN) {
            const _Float16* gs = gsrc + j0 + 64;
            #pragma unroll
            for (int i = 0; i < 8; ++i)
                __builtin_amdgcn_global_load_lds(GPTR(gs + (size_t)i * 8 * NN),
                                                 LPTR(&Ht[buf ^ 1][(w * 64 + i * 8) * 64]), 16, 0, 0);
            #pragma unroll
            for (int kt = 0; kt < 4; ++kt)
                Afn[kt] = *(const half8*)&fb[(size_t)(j0 + 64 + kt * 16 + ln) * CKK + lq * 8];
        }

        // S phase: 4 tiles of 16 keys x 16 q; exp'd p kept in registers.
        // Lane (ln,lq) of tile kt holds P[key = kt*16 + lq*4 + r][q = ln].
        union H4 { half4 h; int2 i; } ph[4];
        #pragma unroll
        for (int kt = 0; kt < 4; ++kt) {
            const f32x4 s = __builtin_amdgcn_mfma_f32_16x16x32_f16(Af[kt], Bg, zero, 0, 0, 0);
            #pragma unroll
            for (int r = 0; r < 4; ++r) {
                const float p = exp2f(fmaf(s[r], LOG2E, -mk));
                psum += p;
                ph[kt].h[r] = (_Float16)p;
            }
        }

        // C-layout -> K32 A-frag: shuffle both tiles, select by dest lq.
        // A[m=ln][k=lq*8+j]: key lq*8+j = (lq>>1)*16 + (lq&1)*8 + j, source
        // lane ln + 32*(lq&1) (+16 for j>=4), regs j%4, tile lq>>1 (+2 for hi).
        union H8 { half8 h; int4 i; } apl, aph;
        {
            const int t0x0 = __shfl(ph[0].i.x, s0lane), t1x0 = __shfl(ph[1].i.x, s0lane);
            const int t0y0 = __shfl(ph[0].i.y, s0lane), t1y0 = __shfl(ph[1].i.y, s0lane);
            const int t0x1 = __shfl(ph[0].i.x, s1lane), t1x1 = __shfl(ph[1].i.x, s1lane);
            const int t0y1 = __shfl(ph[0].i.y, s1lane), t1y1 = __shfl(ph[1].i.y, s1lane);
            apl.i.x = sel ? t1x0 : t0x0;
            apl.i.y = sel ? t1y0 : t0y0;
            apl.i.z = sel ? t1x1 : t0x1;
            apl.i.w = sel ? t1y1 : t0y1;
        }
        {
            const int t2x0 = __shfl(ph[2].i.x, s0lane), t3x0 = __shfl(ph[3].i.x, s0lane);
            const int t2y0 = __shfl(ph[2].i.y, s0lane), t3y0 = __shfl(ph[3].i.y, s0lane);
            const int t2x1 = __shfl(ph[2].i.x, s1lane), t3x1 = __shfl(ph[3].i.x, s1lane);
            const int t2y1 = __shfl(ph[2].i.y, s1lane), t3y1 = __shfl(ph[3].i.y, s1lane);
            aph.i.x = sel ? t3x0 : t2x0;
            aph.i.y = sel ? t3y0 : t2y0;
            aph.i.z = sel ? t3x1 : t2x1;
            aph.i.w = sel ? t3y1 : t2y1;
        }

        // PV: 16 c-tiles x 2 key-halves, B from swizzled LDS (conflict-free)
        #pragma unroll
        for (int ct = 0; ct < 16; ++ct) {
            const int row = ct * 16 + ln;
            const int sg0 = (lq ^ (ln & 7)) * 8;
            const int sg1 = ((4 + lq) ^ (ln & 7)) * 8;
            const half8 Bh0 = *(const half8*)&Ht[buf][row * 64 + sg0];
            const half8 Bh1 = *(const half8*)&Ht[buf][row * 64 + sg1];
            O[ct] = __builtin_amdgcn_mfma_f32_16x16x32_f16(apl.h, Bh0, O[ct], 0, 0, 0);
            O[ct] = __builtin_amdgcn_mfma_f32_16x16x32_f16(aph.h, Bh1, O[ct], 0, 0, 0);
        }

        #pragma unroll
        for (int kt = 0; kt < 4; ++kt) Af[kt] = Afn[kt];
    }

    // ---- rowsum + epilogue (per-wave; o emitted as bf16 hi/lo) ----
    psum += __shfl_xor(psum, 16);
    psum += __shfl_xor(psum, 32);
    float rinv[4];
    #pragma unroll
    for (int r = 0; r < 4; ++r) rinv[r] = 1.0f / __shfl(psum, lq * 4 + r);

    #pragma unroll
    for (int ct = 0; ct < 16; ++ct) {
        const int c = ct * 16 + ln;
        #pragma unroll
        for (int r = 0; r < 4; ++r) {
            const float v = O[ct][r] * rinv[r];
            const unsigned short h = bf16_bits(v);
            const size_t idx = (size_t)(b * NN + qw + lq * 4 + r) * CC + c;
            ohi[idx] = h;
            olo[idx] = bf16_bits(v - bf16_val(h));
        }
    }
}

// ---------------------------------------------------------------------------
// K3: out = gamma * (o @ Wo + bo) + x, A pre-split bf16 (from attn epilogue).
// ---------------------------------------------------------------------------
__global__ __launch_bounds__(256) void out_kernel(
    const unsigned short* __restrict__ ohi, const unsigned short* __restrict__ olo,
    const unsigned short* __restrict__ WThi, const unsigned short* __restrict__ WTlo,
    const float* __restrict__ bo, const float* __restrict__ gamma,
    const float* __restrict__ x, float* __restrict__ out)
{
    const int tid = threadIdx.x, w = tid >> 6, lane = tid & 63;
    const int ln = lane & 15, lq = lane >> 4;
    const int px0 = blockIdx.x * 256 + w * 64;
    const int n0  = blockIdx.y * 64;

    f32x4 acc[4][4];
    #pragma unroll
    for (int i = 0; i < 4; ++i)
        #pragma unroll
        for (int j = 0; j < 4; ++j) acc[i][j] = {0.f, 0.f, 0.f, 0.f};

    #pragma unroll 1
    for (int kc = 0; kc < 8; ++kc) {
        const int k0 = kc * 32;
        short8 Ahi[4], Alo[4];
        #pragma unroll
        for (int mt = 0; mt < 4; ++mt) {
            const size_t aoff = (size_t)(px0 + mt * 16 + ln) * CC + k0 + lq * 8;
            Ahi[mt] = *(const short8*)&ohi[aoff];
            Alo[mt] = *(const short8*)&olo[aoff];
        }
        #pragma unroll
        for (int nt = 0; nt < 4; ++nt) {
            const size_t boff = (size_t)(320 + n0 + nt * 16 + ln) * 256 + k0 + lq * 8;
            const short8 Bhi = *(const short8*)&WThi[boff];
            const short8 Blo = *(const short8*)&WTlo[boff];
            #pragma unroll
            for (int mt = 0; mt < 4; ++mt) {
                acc[mt][nt] = __builtin_amdgcn_mfma_f32_16x16x32_bf16(Ahi[mt], Bhi, acc[mt][nt], 0, 0, 0);
                acc[mt][nt] = __builtin_amdgcn_mfma_f32_16x16x32_bf16(Ahi[mt], Blo, acc[mt][nt], 0, 0, 0);
                acc[mt][nt] = __builtin_amdgcn_mfma_f32_16x16x32_bf16(Alo[mt], Bhi, acc[mt][nt], 0, 0, 0);
            }
        }
    }

    const float gm = gamma[0];
    #pragma unroll
    for (int nt = 0; nt < 4; ++nt) {
        const int c = n0 + nt * 16 + ln;
        const float bias = bo[c];
        #pragma unroll
        for (int mt = 0; mt < 4; ++mt)
            #pragma unroll
            for (int r = 0; r < 4; ++r) {
                const size_t idx = (size_t)(px0 + mt * 16 + lq * 4 + r) * CC + c;
                out[idx] = gm * (acc[mt][nt][r] + bias) + x[idx];
            }
    }
}

// ---------------------------------------------------------------------------
extern "C" void kernel_launch(void* const* d_in, const int* in_sizes, int n_in,
                              void* d_out, int out_size, void* d_ws, size_t ws_size,
                              hipStream_t stream)
{
    (void)in_sizes; (void)n_in; (void)out_size; (void)ws_size;

    const float* x     = (const float*)d_in[0];
    const float* Wf    = (const float*)d_in[1];
    const float* bf    = (const float*)d_in[2];
    const float* Wg    = (const float*)d_in[3];
    const float* bg    = (const float*)d_in[4];
    const float* Wh    = (const float*)d_in[5];
    const float* bh    = (const float*)d_in[6];
    const float* Wo    = (const float*)d_in[7];
    const float* bo    = (const float*)d_in[8];
    const float* gamma = (const float*)d_in[9];
    float* out = (float*)d_out;

    // ws: fbuf 2MB | gbuf 2MB | hhT 16MB | r1 16MB (xhi->ohi) | r2 16MB
    //     (xlo->olo) | WThi 288KB | WTlo 288KB  (total ~52.6MB)
    _Float16* fbuf = (_Float16*)d_ws;
    _Float16* gbuf = fbuf + (size_t)BB * NN * CKK;
    _Float16* hhT  = gbuf + (size_t)BB * NN * CKK;
    unsigned short* r1 = (unsigned short*)(hhT + (size_t)BB * CC * NN);
    unsigned short* r2 = r1 + (size_t)BB * NN * CC;
    unsigned short* WThi = r2 + (size_t)BB * NN * CC;
    unsigned short* WTlo = WThi + (size_t)576 * 256;

    xsplit_kernel<<<BB * NN * CC / (256 * 8), 256, 0, stream>>>(x, r1, r2);
    prep_kernel<<<576, 256, 0, stream>>>(Wf, Wg, Wh, Wo, WThi, WTlo);
    fgh_kernel<<<dim3(BB * NN / 256, 5), 256, 0, stream>>>(r1, r2, WThi, WTlo,
                                                           bf, bg, bh, fbuf, gbuf, hhT);
    attn_kernel<<<BB * NN / 64, 256, 0, stream>>>(fbuf, gbuf, hhT, r1, r2);
    out_kernel<<<dim3(BB * NN / 256, 4), 256, 0, stream>>>(r1, r2, WThi, WTlo,
                                                           bo, gamma, x, out);
}